// Round 7
// baseline (162.791 us; speedup 1.0000x reference)
//
#include <hip/hip_runtime.h>
#include <cstdint>
#include <cstddef>

#define DEV __device__ __forceinline__

typedef __bf16 bf16x8 __attribute__((ext_vector_type(8)));
typedef float f32x4 __attribute__((ext_vector_type(4)));
typedef unsigned short us8 __attribute__((ext_vector_type(8)));
typedef unsigned short us4 __attribute__((ext_vector_type(4)));

typedef const __attribute__((address_space(1))) unsigned int GUI;
typedef __attribute__((address_space(3))) unsigned int LUI;

DEV unsigned short f2bf(float f) {
  unsigned int u = __builtin_bit_cast(unsigned int, f);
  u += 0x7fffu + ((u >> 16) & 1u);
  return (unsigned short)(u >> 16);
}
DEV float bf2f(unsigned short h) {
  unsigned int u = ((unsigned int)h) << 16;
  return __builtin_bit_cast(float, u);
}

// ---------------- convert f32 -> bf16 (vectorized) ----------------
__global__ void k_f32_to_bf16(const float* __restrict__ in, unsigned short* __restrict__ out, int n4) {
  int i = blockIdx.x * blockDim.x + threadIdx.x;
  if (i >= n4) return;
  float4 v = ((const float4*)in)[i];
  us4 o;
  o.x = f2bf(v.x); o.y = f2bf(v.y); o.z = f2bf(v.z); o.w = f2bf(v.w);
  *(us4*)(out + (size_t)i * 4) = o;
}

// ------------- transpose [K,N] f32 -> [N,K] bf16 ------------------
__global__ void k_transpose_bf16(const float* __restrict__ in, unsigned short* __restrict__ out,
                                 int K, int N) {
  __shared__ float tile[32][33];
  int n0 = blockIdx.x * 32, k0 = blockIdx.y * 32;
  int tx = threadIdx.x, ty = threadIdx.y;  // block (32,8)
#pragma unroll
  for (int i = 0; i < 32; i += 8)
    tile[ty + i][tx] = in[(size_t)(k0 + ty + i) * N + n0 + tx];
  __syncthreads();
#pragma unroll
  for (int i = 0; i < 32; i += 8)
    out[(size_t)(n0 + ty + i) * K + k0 + tx] = f2bf(tile[tx][ty + i]);
}

// --------- fused transpose of four 512x512 f32 -> bf16 [N,K] ------
__global__ void k_transpose4(const float* __restrict__ p0, const float* __restrict__ p1,
                             const float* __restrict__ p2, const float* __restrict__ p3,
                             unsigned short* __restrict__ base) {
  __shared__ float tile[32][33];
  const float* in = blockIdx.z == 0 ? p0 : blockIdx.z == 1 ? p1 : blockIdx.z == 2 ? p2 : p3;
  unsigned short* out = base + (size_t)blockIdx.z * 262144;
  int n0 = blockIdx.x * 32, k0 = blockIdx.y * 32;
  int tx = threadIdx.x, ty = threadIdx.y;  // block (32,8)
#pragma unroll
  for (int i = 0; i < 32; i += 8)
    tile[ty + i][tx] = in[(size_t)(k0 + ty + i) * 512 + n0 + tx];
  __syncthreads();
#pragma unroll
  for (int i = 0; i < 32; i += 8)
    out[(size_t)(n0 + ty + i) * 512 + k0 + tx] = f2bf(tile[tx][ty + i]);
}

// ---------------- concat q/k/v biases -----------------------------
__global__ void k_concat_bias(const float* __restrict__ bq, const float* __restrict__ bk,
                              const float* __restrict__ bv, float* __restrict__ out) {
  int i = blockIdx.x * blockDim.x + threadIdx.x;  // 1536
  float v = (i < 512) ? bq[i] : (i < 1024 ? bk[i - 512] : bv[i - 1024]);
  out[i] = v;
}

// --------- bf16 MFMA GEMM body: 256x256 tile, BK=32, 4-slot ring --
// A: [M,K] bf16 row-major, BT: [N,K] bf16 row-major.  M fixed = 8192.
// MODE 0: bf16 out; MODE 2: bf16 out + exact GELU.
// SPLITK: partial z writes (bf16) to outp + z*8192*N; bias only on z==0.
// Deep pipeline (T3/T4): 4-slot LDS ring (32KB/slot, 128KB total),
// prologue stages tiles 0..2, each iter issues tile t+3 then waits
// vmcnt(12) -> 3 tiles ALWAYS in flight, never drained mid-loop.
// Slot reuse is write-after-read safe: stage of t+3 (slot (t+3)&3) is
// issued after barrier2 of iter t-1, which retired all reads of that slot.
// LDS layout (pair-packed): global row r, k-chunk q (8 bf16) lives at
// lds-row R=r>>1, chunk d=((r&1)*4+q)^(R&7) -> linear gload_lds dests,
// 2-way (free) bank spread on both stage-writes and ds_read_b128.
template <int MODE, int SPLITK>
DEV void gemm_body(const unsigned short* __restrict__ A,
                   const unsigned short* __restrict__ BT,
                   const float* __restrict__ bias,
                   unsigned short* __restrict__ outp,
                   int K, int N) {
  __shared__ __align__(16) unsigned short As[4 * 8192];
  __shared__ __align__(16) unsigned short Bs[4 * 8192];
  const int tid = threadIdx.x;
  const int wave = tid >> 6, lane = tid & 63;
  const int wm = wave >> 2, wn = wave & 3;
  const int q = lane >> 4, l15 = lane & 15;

  // XCD-bijective block swizzle, A-panel-grouped ((bx,z) fastest)
  const int nx = gridDim.x, ny = gridDim.y;
  const int nwg = nx * ny * SPLITK;
  const int lid = (blockIdx.z * ny + blockIdx.y) * nx + blockIdx.x;
  const int q8 = nwg >> 3, r8 = nwg & 7;
  const int xcd = lid & 7, slot0 = lid >> 3;
  const int wid = (xcd < r8 ? xcd * (q8 + 1) : r8 * (q8 + 1) + (xcd - r8) * q8) + slot0;
  const int nbz = nx * SPLITK;
  const int bxz = wid % nbz;
  const int by  = wid / nbz;
  const int bx  = bxz % nx;
  const int z   = bxz / nx;

  const int rbase = by * 256;
  const int nbase = bx * 256;
  const int kper = K / SPLITK;
  const int nkt = kper >> 5;           // K-steps of 32 (>= 4 at all call sites)
  const int kb = z * kper;

  // preload bias, drain before pipeline (vmcnt counting must stay exact)
  float bv_[4];
#pragma unroll
  for (int n = 0; n < 4; ++n) {
    int gcol = nbase + wn * 64 + n * 16 + l15;
    bv_[n] = (z == 0) ? bias[gcol] : 0.f;
  }
  asm volatile("s_waitcnt vmcnt(0)" ::: "memory");

  // stage one 256x32 A-tile + B-tile (16KB each): 4 gload_lds per thread
  auto STAGE = [&](int slot, int k0) {
#pragma unroll
    for (int i = 0; i < 2; ++i) {
      int s = i * 512 + tid;                 // 16B-slot in [0,1024)
      int R = s >> 3;                        // lds-row 0..127
      int c = (s & 7) ^ (R & 7);             // source data-chunk for linear dest
      int r = 2 * R + (c >> 2);              // global tile row 0..255
      int kl = (c & 3) << 3;                 // k offset 0..24
      const unsigned short* ga = A + (size_t)(rbase + r) * K + k0 + kl;
      const unsigned short* gb = BT + (size_t)(nbase + r) * K + k0 + kl;
      const int dst = slot * 8192 + (i * 512 + wave * 64) * 8;  // wave-uniform base
      __builtin_amdgcn_global_load_lds((GUI*)ga, (LUI*)(As + dst), 16, 0, 0);
      __builtin_amdgcn_global_load_lds((GUI*)gb, (LUI*)(Bs + dst), 16, 0, 0);
    }
  };

  f32x4 acc[8][4] = {};
  STAGE(0, kb);
  STAGE(1, kb + 32);
  STAGE(2, kb + 64);

  for (int t = 0; t < nkt; ++t) {
    if (t + 3 < nkt) {
      STAGE((t + 3) & 3, kb + (t + 3) * 32);
      asm volatile("s_waitcnt vmcnt(12)" ::: "memory");  // tile t landed; 3 in flight
    } else if (t + 2 < nkt) {
      asm volatile("s_waitcnt vmcnt(8)" ::: "memory");
    } else if (t + 1 < nkt) {
      asm volatile("s_waitcnt vmcnt(4)" ::: "memory");
    } else {
      asm volatile("s_waitcnt vmcnt(0)" ::: "memory");
    }
    __builtin_amdgcn_s_barrier();

    const unsigned short* Ab = As + (t & 3) * 8192;
    const unsigned short* Bb = Bs + (t & 3) * 8192;
    bf16x8 af[8], bfr[4];
#pragma unroll
    for (int m = 0; m < 8; ++m) {
      int rr = wm * 128 + m * 16 + l15;
      int R = rr >> 1;
      int d = (((rr & 1) << 2) + q) ^ (R & 7);
      af[m] = __builtin_bit_cast(bf16x8, *(const us8*)(Ab + R * 64 + d * 8));
    }
#pragma unroll
    for (int n = 0; n < 4; ++n) {
      int rr = wn * 64 + n * 16 + l15;
      int R = rr >> 1;
      int d = (((rr & 1) << 2) + q) ^ (R & 7);
      bfr[n] = __builtin_bit_cast(bf16x8, *(const us8*)(Bb + R * 64 + d * 8));
    }
    asm volatile("s_waitcnt lgkmcnt(0)" ::: "memory");
    __builtin_amdgcn_sched_barrier(0);
    __builtin_amdgcn_s_setprio(1);
#pragma unroll
    for (int m = 0; m < 8; ++m)
#pragma unroll
      for (int n = 0; n < 4; ++n)
        acc[m][n] = __builtin_amdgcn_mfma_f32_16x16x32_bf16(af[m], bfr[n], acc[m][n], 0, 0, 0);
    __builtin_amdgcn_s_setprio(0);
    __builtin_amdgcn_s_barrier();
  }

  unsigned short* opv = outp + (size_t)z * 8192 * N;
#pragma unroll
  for (int m = 0; m < 8; ++m) {
    int grow0 = rbase + wm * 128 + m * 16 + (q << 2);
#pragma unroll
    for (int n = 0; n < 4; ++n) {
      int gcol = nbase + wn * 64 + n * 16 + l15;
#pragma unroll
      for (int r = 0; r < 4; ++r) {
        float v = acc[m][n][r] + bv_[n];
        if (MODE == 2) v = 0.5f * v * (1.0f + erff(v * 0.70710678118654752f));
        opv[(size_t)(grow0 + r) * N + gcol] = f2bf(v);
      }
    }
  }
}

// Named wrappers so rocprof distinguishes the four GEMMs.
__global__ __launch_bounds__(512) void k_qkv(const unsigned short* __restrict__ A,
                                             const unsigned short* __restrict__ BT,
                                             const float* __restrict__ bias,
                                             unsigned short* __restrict__ outp, int K, int N) {
  gemm_body<0, 1>(A, BT, bias, outp, K, N);
}
__global__ __launch_bounds__(512) void k_wo(const unsigned short* __restrict__ A,
                                            const unsigned short* __restrict__ BT,
                                            const float* __restrict__ bias,
                                            unsigned short* __restrict__ outp, int K, int N) {
  gemm_body<0, 4>(A, BT, bias, outp, K, N);
}
__global__ __launch_bounds__(512) void k_ffn1(const unsigned short* __restrict__ A,
                                              const unsigned short* __restrict__ BT,
                                              const float* __restrict__ bias,
                                              unsigned short* __restrict__ outp, int K, int N) {
  gemm_body<2, 1>(A, BT, bias, outp, K, N);
}
__global__ __launch_bounds__(512) void k_ffn2(const unsigned short* __restrict__ A,
                                              const unsigned short* __restrict__ BT,
                                              const float* __restrict__ bias,
                                              unsigned short* __restrict__ outp, int K, int N) {
  gemm_body<0, 4>(A, BT, bias, outp, K, N);
}

// ---------------- windowed causal attention -----------------------
__global__ __launch_bounds__(64) void k_attn(const unsigned short* __restrict__ qkv,
                                             unsigned short* __restrict__ attnb) {
  __shared__ float Qt[64 * 67];  // [d][q]
  __shared__ float Kt[64 * 75];  // [d][t]
  __shared__ float P[64 * 12];   // [q][jj]

  const int lane = threadIdx.x;
  const int bid = blockIdx.x;          // 1024 = 32 chunks x 32 bh
  const int chunk = bid & 31;
  const int bh = bid >> 5;
  const int h = bh & 7, b = bh >> 3;
  const int i0 = chunk * 64;
  const int b2048 = b * 2048;
  const int h64 = h * 64;

#pragma unroll 8
  for (int r = 0; r < 73; ++r) {
    int jloc = i0 - 9 + r;
    int jc = jloc < 0 ? 0 : jloc;
    Kt[lane * 75 + r] = bf2f(qkv[(size_t)(b2048 + jc) * 1536 + 512 + h64 + lane]);
  }
#pragma unroll 8
  for (int r = 0; r < 64; ++r) {
    Qt[lane * 67 + r] = bf2f(qkv[(size_t)(b2048 + i0 + r) * 1536 + h64 + lane]);
  }
  __syncthreads();

  float s[10];
#pragma unroll
  for (int jj = 0; jj < 10; ++jj) s[jj] = 0.f;
#pragma unroll
  for (int d = 0; d < 64; ++d) {
    float qd = Qt[d * 67 + lane];
#pragma unroll
    for (int jj = 0; jj < 10; ++jj)
      s[jj] = fmaf(qd, Kt[d * 75 + lane + jj], s[jj]);
  }
  const int iG = i0 + lane;
#pragma unroll
  for (int jj = 0; jj < 10; ++jj)
    s[jj] = (iG - 9 + jj >= 0) ? s[jj] * 0.125f : -1e30f;
  float mx = s[9];
#pragma unroll
  for (int jj = 0; jj < 9; ++jj) mx = fmaxf(mx, s[jj]);
  float den = 0.f;
#pragma unroll
  for (int jj = 0; jj < 10; ++jj) {
    s[jj] = __expf(s[jj] - mx);
    den += s[jj];
  }
  float inv = 1.f / den;
#pragma unroll
  for (int jj = 0; jj < 10; ++jj) P[lane * 12 + jj] = s[jj] * inv;
  __syncthreads();

  for (int q0 = 0; q0 < 64; q0 += 4) {
    float vv[13];
#pragma unroll
    for (int t = 0; t < 13; ++t) {
      int jloc = i0 + q0 - 9 + t;
      int jc = jloc < 0 ? 0 : jloc;
      vv[t] = bf2f(qkv[(size_t)(b2048 + jc) * 1536 + 1024 + h64 + lane]);
    }
#pragma unroll
    for (int qq = 0; qq < 4; ++qq) {
      const int q = q0 + qq;
      const float* pp = &P[q * 12];
      float o = 0.f;
#pragma unroll
      for (int jj = 0; jj < 10; ++jj) o = fmaf(pp[jj], vv[qq + jj], o);
      attnb[(size_t)(b2048 + i0 + q) * 512 + h64 + lane] = f2bf(o);
    }
  }
}

// ---------------- residual + LayerNorm ----------------------------
// y = LN(res + sum_{p<NP} add[p]).  V0: res f32 -> out bf16.  V1: res bf16 -> out f32.
template <int V, int NP>
DEV void ln_body(const void* __restrict__ resv,
                 const unsigned short* __restrict__ add,
                 const float* __restrict__ w,
                 const float* __restrict__ bb,
                 void* __restrict__ outp) {
  const size_t PLANE = (size_t)8192 * 512;
  const int wave = threadIdx.x >> 6, lane = threadIdx.x & 63;
  const int row = blockIdx.x * 4 + wave;
  float x[8];
  if (V == 0) {
    const float4* r4 = (const float4*)((const float*)resv + (size_t)row * 512) + lane * 2;
    float4 a = r4[0], b = r4[1];
    x[0] = a.x; x[1] = a.y; x[2] = a.z; x[3] = a.w;
    x[4] = b.x; x[5] = b.y; x[6] = b.z; x[7] = b.w;
  } else {
    us8 r = *(const us8*)((const unsigned short*)resv + (size_t)row * 512 + lane * 8);
#pragma unroll
    for (int j = 0; j < 8; ++j) x[j] = bf2f(r[j]);
  }
#pragma unroll
  for (int p = 0; p < NP; ++p) {
    us8 a = *(const us8*)(add + p * PLANE + (size_t)row * 512 + lane * 8);
#pragma unroll
    for (int j = 0; j < 8; ++j) x[j] += bf2f(a[j]);
  }
  float sum = 0.f, ss = 0.f;
#pragma unroll
  for (int j = 0; j < 8; ++j) {
    sum += x[j];
    ss += x[j] * x[j];
  }
#pragma unroll
  for (int m = 32; m >= 1; m >>= 1) {
    sum += __shfl_xor(sum, m);
    ss += __shfl_xor(ss, m);
  }
  const float mu = sum * (1.f / 512.f);
  float var = ss * (1.f / 512.f) - mu * mu;
  const float rstd = rsqrtf(var + 1e-5f);
  const int c = lane * 8;
  float o[8];
#pragma unroll
  for (int j = 0; j < 8; ++j) o[j] = (x[j] - mu) * rstd * w[c + j] + bb[c + j];
  if (V == 0) {
    us8 u;
#pragma unroll
    for (int j = 0; j < 8; ++j) u[j] = f2bf(o[j]);
    *(us8*)((unsigned short*)outp + (size_t)row * 512 + c) = u;
  } else {
    float4 u0, u1;
    u0.x = o[0]; u0.y = o[1]; u0.z = o[2]; u0.w = o[3];
    u1.x = o[4]; u1.y = o[5]; u1.z = o[6]; u1.w = o[7];
    float4* o4 = (float4*)((float*)outp + (size_t)row * 512 + c);
    o4[0] = u0; o4[1] = u1;
  }
}

__global__ __launch_bounds__(256) void k_ln_mid(const float* __restrict__ res,
                                                const unsigned short* __restrict__ add,
                                                const float* __restrict__ w,
                                                const float* __restrict__ bb,
                                                unsigned short* __restrict__ outp) {
  ln_body<0, 4>(res, add, w, bb, outp);
}
__global__ __launch_bounds__(256) void k_ln_out(const unsigned short* __restrict__ res,
                                                const unsigned short* __restrict__ add,
                                                const float* __restrict__ w,
                                                const float* __restrict__ bb,
                                                float* __restrict__ outp) {
  ln_body<1, 4>(res, add, w, bb, outp);
}

extern "C" void kernel_launch(void* const* d_in, const int* in_sizes, int n_in,
                              void* d_out, int out_size, void* d_ws, size_t ws_size,
                              hipStream_t stream) {
  const float* z    = (const float*)d_in[0];
  const float* Wq   = (const float*)d_in[1];
  const float* bq   = (const float*)d_in[2];
  const float* Wk   = (const float*)d_in[3];
  const float* bk   = (const float*)d_in[4];
  const float* Wv   = (const float*)d_in[5];
  const float* bv   = (const float*)d_in[6];
  const float* Wo   = (const float*)d_in[7];
  const float* bo   = (const float*)d_in[8];
  const float* ln1w = (const float*)d_in[9];
  const float* ln1b = (const float*)d_in[10];
  const float* W1   = (const float*)d_in[11];
  const float* b1   = (const float*)d_in[12];
  const float* W2   = (const float*)d_in[13];
  const float* b2   = (const float*)d_in[14];
  const float* ln2w = (const float*)d_in[15];
  const float* ln2b = (const float*)d_in[16];
  float* out = (float*)d_out;

  char* ws = (char*)d_ws;
  size_t off = 0;
  auto alloc = [&](size_t bytes) {
    char* p = ws + off;
    off += (bytes + 255) & ~(size_t)255;
    return p;
  };
  unsigned short* Wsq   = (unsigned short*)alloc((size_t)2048 * 512 * 2);  // WqT|WkT|WvT|WoT
  unsigned short* WTqkv = Wsq;
  unsigned short* WoT   = Wsq + (size_t)1536 * 512;
  unsigned short* W1T   = (unsigned short*)alloc((size_t)2048 * 512 * 2);
  unsigned short* W2T   = (unsigned short*)alloc((size_t)512 * 2048 * 2);
  float*          biasqkv = (float*)alloc(1536 * 4);
  unsigned short* zb    = (unsigned short*)alloc((size_t)8192 * 512 * 2);
  unsigned short* qkvb  = (unsigned short*)alloc((size_t)8192 * 1536 * 2);
  unsigned short* attnb = (unsigned short*)alloc((size_t)8192 * 512 * 2);
  unsigned short* p1    = (unsigned short*)alloc((size_t)4 * 8192 * 512 * 2);  // 4 split-K planes
  unsigned short* z1b   = zb;    // reuse (zb dead after QKV GEMM)
  unsigned short* ff    = qkvb;  // reuse qkvb+attnb (contiguous 33.5MB; dead after Wo GEMM)

  dim3 tb(32, 8);
  k_f32_to_bf16<<<4096, 256, 0, stream>>>(z, zb, 1048576);
  k_transpose4<<<dim3(16, 16, 4), tb, 0, stream>>>(Wq, Wk, Wv, Wo, Wsq);
  k_transpose_bf16<<<dim3(64, 16), tb, 0, stream>>>(W1, W1T, 512, 2048);
  k_transpose_bf16<<<dim3(16, 64), tb, 0, stream>>>(W2, W2T, 2048, 512);
  k_concat_bias<<<6, 256, 0, stream>>>(bq, bk, bv, biasqkv);

  // QKV: [8192,512] @ [512,1536] -> qkvb (bf16), 192 blocks
  k_qkv<<<dim3(6, 32), 512, 0, stream>>>(zb, WTqkv, biasqkv, qkvb, 512, 1536);
  // windowed attention
  k_attn<<<1024, 64, 0, stream>>>(qkvb, attnb);
  // Wo proj: [8192,512] @ [512,512], split-K=4 -> p1[0..3], 256 blocks
  k_wo<<<dim3(2, 32, 4), 512, 0, stream>>>(attnb, WoT, bo, p1, 512, 512);
  // z1b = LN(z + p1[0..3])  (bf16)
  k_ln_mid<<<2048, 256, 0, stream>>>(z, p1, ln1w, ln1b, z1b);
  // FFN1: [8192,512] @ [512,2048] + GELU -> ff (bf16), 256 blocks
  k_ffn1<<<dim3(8, 32), 512, 0, stream>>>(z1b, W1T, b1, ff, 512, 2048);
  // FFN2: [8192,2048] @ [2048,512], split-K=4 -> p1[0..3], 256 blocks
  k_ffn2<<<dim3(2, 32, 4), 512, 0, stream>>>(ff, W2T, b2, p1, 2048, 512);
  // out = LN(z1b + p1[0..3])  (f32)
  k_ln_out<<<2048, 256, 0, stream>>>(z1b, p1, ln2w, ln2b, out);
}

// Round 8
// 143.556 us; speedup vs baseline: 1.1340x; 1.1340x over previous
//
#include <hip/hip_runtime.h>
#include <cstdint>
#include <cstddef>

#define DEV __device__ __forceinline__

typedef __bf16 bf16x8 __attribute__((ext_vector_type(8)));
typedef float f32x4 __attribute__((ext_vector_type(4)));
typedef unsigned short us8 __attribute__((ext_vector_type(8)));
typedef unsigned short us4 __attribute__((ext_vector_type(4)));

typedef const __attribute__((address_space(1))) unsigned int GUI;
typedef __attribute__((address_space(3))) unsigned int LUI;

DEV unsigned short f2bf(float f) {
  unsigned int u = __builtin_bit_cast(unsigned int, f);
  u += 0x7fffu + ((u >> 16) & 1u);
  return (unsigned short)(u >> 16);
}
DEV float bf2f(unsigned short h) {
  unsigned int u = ((unsigned int)h) << 16;
  return __builtin_bit_cast(float, u);
}

// ---------- fused prep: z->bf16, weight transposes, bias concat ----------
// job ids (blockIdx.x):
//   [0,4096)      convert z (f32 -> bf16), 1024 floats/block
//   [4096,5120)   transpose Wq|Wk|Wv|Wo (4 x 256 32x32 tiles) -> Wsq
//   [5120,6144)   transpose W1 [512,2048] -> W1T [2048,512]
//   [6144,7168)   transpose W2 [2048,512] -> W2T [512,2048]
//   7168          concat q/k/v biases
DEV void tr32(const float* __restrict__ in, unsigned short* __restrict__ out,
              int K, int N, int k0, int n0) {
  __shared__ float tile[32][33];
  const int tx = threadIdx.x & 31, ty = threadIdx.x >> 5;  // 256 thr = 32x8
#pragma unroll
  for (int i = 0; i < 32; i += 8)
    tile[ty + i][tx] = in[(size_t)(k0 + ty + i) * N + n0 + tx];
  __syncthreads();
#pragma unroll
  for (int i = 0; i < 32; i += 8)
    out[(size_t)(n0 + ty + i) * K + k0 + tx] = f2bf(tile[tx][ty + i]);
}

__global__ __launch_bounds__(256) void k_prep(
    const float* __restrict__ z, unsigned short* __restrict__ zb,
    const float* __restrict__ Wq, const float* __restrict__ Wk,
    const float* __restrict__ Wv, const float* __restrict__ Wo,
    unsigned short* __restrict__ Wsq,
    const float* __restrict__ W1, unsigned short* __restrict__ W1T,
    const float* __restrict__ W2, unsigned short* __restrict__ W2T,
    const float* __restrict__ bq, const float* __restrict__ bk,
    const float* __restrict__ bv, float* __restrict__ biasqkv) {
  const int j = blockIdx.x;
  const int tid = threadIdx.x;
  if (j < 4096) {
    int i = j * 256 + tid;  // float4 index, 4096*256*4 = 4.19M floats
    float4 v = ((const float4*)z)[i];
    us4 o;
    o.x = f2bf(v.x); o.y = f2bf(v.y); o.z = f2bf(v.z); o.w = f2bf(v.w);
    *(us4*)(zb + (size_t)i * 4) = o;
  } else if (j < 5120) {
    int t = j - 4096;
    int mat = t >> 8, tile = t & 255;
    const float* in = mat == 0 ? Wq : mat == 1 ? Wk : mat == 2 ? Wv : Wo;
    tr32(in, Wsq + (size_t)mat * 262144, 512, 512, (tile >> 4) * 32, (tile & 15) * 32);
  } else if (j < 6144) {
    int t = j - 5120;  // W1: K=512,N=2048 -> 64 x 16 tiles
    tr32(W1, W1T, 512, 2048, (t / 64) * 32, (t % 64) * 32);
  } else if (j < 7168) {
    int t = j - 6144;  // W2: K=2048,N=512 -> 16 x 64 tiles
    tr32(W2, W2T, 2048, 512, (t / 16) * 32, (t % 16) * 32);
  } else {
    for (int i = tid; i < 1536; i += 256)
      biasqkv[i] = (i < 512) ? bq[i] : (i < 1024 ? bk[i - 512] : bv[i - 1024]);
  }
}

// --------- bf16 MFMA GEMM body, 256x256 tile, BK=64, 8 waves ------
// (round-6 structure: best measured; deep ring regressed, reverted)
// A: [M,K] bf16 row-major, BT: [N,K] bf16 row-major.  M fixed = 8192.
// MODE 0: bf16 out; MODE 2: bf16 out + exact GELU.
// SPLITK: partial z writes (bf16) to outp + z*8192*N; bias only on z==0.
// XCD swizzle, A-panel-grouped: (bx,z) walks fastest within an XCD chunk
// -> A-panel (<=1MB) + whole B (<=2MB) are XCD-L2-resident.
template <int MODE, int SPLITK>
DEV void gemm_body(const unsigned short* __restrict__ A,
                   const unsigned short* __restrict__ BT,
                   const float* __restrict__ bias,
                   unsigned short* __restrict__ outp,
                   int K, int N) {
  __shared__ __align__(16) unsigned short As[2 * 16384];
  __shared__ __align__(16) unsigned short Bs[2 * 16384];
  const int tid = threadIdx.x;
  const int wave = tid >> 6, lane = tid & 63;
  const int wm = wave >> 2, wn = wave & 3;

  const int nx = gridDim.x, ny = gridDim.y;
  const int nwg = nx * ny * SPLITK;
  const int lid = (blockIdx.z * ny + blockIdx.y) * nx + blockIdx.x;
  const int q8 = nwg >> 3, r8 = nwg & 7;
  const int xcd = lid & 7, slot = lid >> 3;
  const int wid = (xcd < r8 ? xcd * (q8 + 1) : r8 * (q8 + 1) + (xcd - r8) * q8) + slot;
  const int nbz = nx * SPLITK;
  const int bxz = wid % nbz;   // fastest: B-tile/K-slice
  const int by  = wid / nbz;   // slowest: A-panel
  const int bx  = bxz % nx;
  const int z   = bxz / nx;

  const int rbase = by * 256;
  const int nbase = bx * 256;
  const int nkt = (K / SPLITK) >> 6;       // K-steps of 64
  const int kb = z * (K / SPLITK);

  // preload bias, drain before pipeline (vmcnt counting must stay exact)
  float bv_[4];
#pragma unroll
  for (int n = 0; n < 4; ++n) {
    int gcol = nbase + wn * 64 + n * 16 + (lane & 15);
    bv_[n] = (z == 0) ? bias[gcol] : 0.f;
  }
  asm volatile("s_waitcnt vmcnt(0)" ::: "memory");

  // stage one 256x64 A-tile + B-tile (32KB each): 4 slots/thread/side
  auto STAGE = [&](int buf, int k0) {
#pragma unroll
    for (int t = 0; t < 4; ++t) {
      int s = t * 512 + tid;                        // 16B-slot in [0,2048)
      int row = s >> 3;
      int col = ((s & 7) ^ (row & 7)) << 3;         // chunk-XOR swizzled source
      const unsigned short* ga = A + (size_t)(rbase + row) * K + k0 + col;
      const unsigned short* gb = BT + (size_t)(nbase + row) * K + k0 + col;
      const int dst = buf * 16384 + (t * 512 + wave * 64) * 8;  // wave-uniform base
      __builtin_amdgcn_global_load_lds((GUI*)ga, (LUI*)(As + dst), 16, 0, 0);
      __builtin_amdgcn_global_load_lds((GUI*)gb, (LUI*)(Bs + dst), 16, 0, 0);
    }
  };

  f32x4 acc[8][4] = {};
  STAGE(0, kb);

  for (int kt = 0; kt < nkt; ++kt) {
    const int cur = kt & 1;
    if (kt + 1 < nkt) {
      STAGE(cur ^ 1, kb + (kt + 1) * 64);
      asm volatile("s_waitcnt vmcnt(8)" ::: "memory");  // drain cur, keep next in flight
    } else {
      asm volatile("s_waitcnt vmcnt(0)" ::: "memory");
    }
    __builtin_amdgcn_s_barrier();

#pragma unroll
    for (int ks = 0; ks < 2; ++ks) {
      bf16x8 af[8], bfr[4];
#pragma unroll
      for (int m = 0; m < 8; ++m) {
        int row = wm * 128 + m * 16 + (lane & 15);
        int ch = (ks * 4 + (lane >> 4)) ^ (row & 7);
        af[m] = __builtin_bit_cast(bf16x8, *(const us8*)(As + cur * 16384 + row * 64 + ch * 8));
      }
#pragma unroll
      for (int n = 0; n < 4; ++n) {
        int row = wn * 64 + n * 16 + (lane & 15);
        int ch = (ks * 4 + (lane >> 4)) ^ (row & 7);
        bfr[n] = __builtin_bit_cast(bf16x8, *(const us8*)(Bs + cur * 16384 + row * 64 + ch * 8));
      }
      __builtin_amdgcn_s_setprio(1);
#pragma unroll
      for (int m = 0; m < 8; ++m)
#pragma unroll
        for (int n = 0; n < 4; ++n)
          acc[m][n] = __builtin_amdgcn_mfma_f32_16x16x32_bf16(af[m], bfr[n], acc[m][n], 0, 0, 0);
      __builtin_amdgcn_s_setprio(0);
    }
    asm volatile("s_waitcnt lgkmcnt(0)" ::: "memory");
    __builtin_amdgcn_s_barrier();
  }

  unsigned short* opv = outp + (size_t)z * 8192 * N;
#pragma unroll
  for (int m = 0; m < 8; ++m) {
    int grow0 = rbase + wm * 128 + m * 16 + ((lane >> 4) << 2);
#pragma unroll
    for (int n = 0; n < 4; ++n) {
      int gcol = nbase + wn * 64 + n * 16 + (lane & 15);
#pragma unroll
      for (int r = 0; r < 4; ++r) {
        float v = acc[m][n][r] + bv_[n];
        if (MODE == 2) v = 0.5f * v * (1.0f + erff(v * 0.70710678118654752f));
        opv[(size_t)(grow0 + r) * N + gcol] = f2bf(v);
      }
    }
  }
}

// Named wrappers so rocprof distinguishes the four GEMMs.
__global__ __launch_bounds__(512) void k_qkv(const unsigned short* __restrict__ A,
                                             const unsigned short* __restrict__ BT,
                                             const float* __restrict__ bias,
                                             unsigned short* __restrict__ outp, int K, int N) {
  gemm_body<0, 1>(A, BT, bias, outp, K, N);
}
__global__ __launch_bounds__(512) void k_wo(const unsigned short* __restrict__ A,
                                            const unsigned short* __restrict__ BT,
                                            const float* __restrict__ bias,
                                            unsigned short* __restrict__ outp, int K, int N) {
  gemm_body<0, 4>(A, BT, bias, outp, K, N);
}
__global__ __launch_bounds__(512) void k_ffn1(const unsigned short* __restrict__ A,
                                              const unsigned short* __restrict__ BT,
                                              const float* __restrict__ bias,
                                              unsigned short* __restrict__ outp, int K, int N) {
  gemm_body<2, 1>(A, BT, bias, outp, K, N);
}
__global__ __launch_bounds__(512) void k_ffn2(const unsigned short* __restrict__ A,
                                              const unsigned short* __restrict__ BT,
                                              const float* __restrict__ bias,
                                              unsigned short* __restrict__ outp, int K, int N) {
  gemm_body<0, 4>(A, BT, bias, outp, K, N);
}

// ---------------- windowed causal attention -----------------------
__global__ __launch_bounds__(64) void k_attn(const unsigned short* __restrict__ qkv,
                                             unsigned short* __restrict__ attnb) {
  __shared__ float Qt[64 * 67];  // [d][q]
  __shared__ float Kt[64 * 75];  // [d][t]
  __shared__ float P[64 * 12];   // [q][jj]

  const int lane = threadIdx.x;
  const int bid = blockIdx.x;          // 1024 = 32 chunks x 32 bh
  const int chunk = bid & 31;
  const int bh = bid >> 5;
  const int h = bh & 7, b = bh >> 3;
  const int i0 = chunk * 64;
  const int b2048 = b * 2048;
  const int h64 = h * 64;

#pragma unroll 8
  for (int r = 0; r < 73; ++r) {
    int jloc = i0 - 9 + r;
    int jc = jloc < 0 ? 0 : jloc;
    Kt[lane * 75 + r] = bf2f(qkv[(size_t)(b2048 + jc) * 1536 + 512 + h64 + lane]);
  }
#pragma unroll 8
  for (int r = 0; r < 64; ++r) {
    Qt[lane * 67 + r] = bf2f(qkv[(size_t)(b2048 + i0 + r) * 1536 + h64 + lane]);
  }
  __syncthreads();

  float s[10];
#pragma unroll
  for (int jj = 0; jj < 10; ++jj) s[jj] = 0.f;
#pragma unroll
  for (int d = 0; d < 64; ++d) {
    float qd = Qt[d * 67 + lane];
#pragma unroll
    for (int jj = 0; jj < 10; ++jj)
      s[jj] = fmaf(qd, Kt[d * 75 + lane + jj], s[jj]);
  }
  const int iG = i0 + lane;
#pragma unroll
  for (int jj = 0; jj < 10; ++jj)
    s[jj] = (iG - 9 + jj >= 0) ? s[jj] * 0.125f : -1e30f;
  float mx = s[9];
#pragma unroll
  for (int jj = 0; jj < 9; ++jj) mx = fmaxf(mx, s[jj]);
  float den = 0.f;
#pragma unroll
  for (int jj = 0; jj < 10; ++jj) {
    s[jj] = __expf(s[jj] - mx);
    den += s[jj];
  }
  float inv = 1.f / den;
#pragma unroll
  for (int jj = 0; jj < 10; ++jj) P[lane * 12 + jj] = s[jj] * inv;
  __syncthreads();

  for (int q0 = 0; q0 < 64; q0 += 4) {
    float vv[13];
#pragma unroll
    for (int t = 0; t < 13; ++t) {
      int jloc = i0 + q0 - 9 + t;
      int jc = jloc < 0 ? 0 : jloc;
      vv[t] = bf2f(qkv[(size_t)(b2048 + jc) * 1536 + 1024 + h64 + lane]);
    }
#pragma unroll
    for (int qq = 0; qq < 4; ++qq) {
      const int q = q0 + qq;
      const float* pp = &P[q * 12];
      float o = 0.f;
#pragma unroll
      for (int jj = 0; jj < 10; ++jj) o = fmaf(pp[jj], vv[qq + jj], o);
      attnb[(size_t)(b2048 + i0 + q) * 512 + h64 + lane] = f2bf(o);
    }
  }
}

// ---------------- residual + LayerNorm ----------------------------
// y = LN(res_bf16 + sum_{p<NP} add[p]).  OUTF32=0 -> bf16 out, 1 -> f32 out.
template <int OUTF32, int NP>
DEV void ln_body(const unsigned short* __restrict__ res,
                 const unsigned short* __restrict__ add,
                 const float* __restrict__ w,
                 const float* __restrict__ bb,
                 void* __restrict__ outp) {
  const size_t PLANE = (size_t)8192 * 512;
  const int wave = threadIdx.x >> 6, lane = threadIdx.x & 63;
  const int row = blockIdx.x * 4 + wave;
  float x[8];
  us8 r = *(const us8*)(res + (size_t)row * 512 + lane * 8);
#pragma unroll
  for (int j = 0; j < 8; ++j) x[j] = bf2f(r[j]);
#pragma unroll
  for (int p = 0; p < NP; ++p) {
    us8 a = *(const us8*)(add + p * PLANE + (size_t)row * 512 + lane * 8);
#pragma unroll
    for (int j = 0; j < 8; ++j) x[j] += bf2f(a[j]);
  }
  float sum = 0.f, ss = 0.f;
#pragma unroll
  for (int j = 0; j < 8; ++j) {
    sum += x[j];
    ss += x[j] * x[j];
  }
#pragma unroll
  for (int m = 32; m >= 1; m >>= 1) {
    sum += __shfl_xor(sum, m);
    ss += __shfl_xor(ss, m);
  }
  const float mu = sum * (1.f / 512.f);
  float var = ss * (1.f / 512.f) - mu * mu;
  const float rstd = rsqrtf(var + 1e-5f);
  const int c = lane * 8;
  float o[8];
#pragma unroll
  for (int j = 0; j < 8; ++j) o[j] = (x[j] - mu) * rstd * w[c + j] + bb[c + j];
  if (OUTF32 == 0) {
    us8 u;
#pragma unroll
    for (int j = 0; j < 8; ++j) u[j] = f2bf(o[j]);
    *(us8*)((unsigned short*)outp + (size_t)row * 512 + c) = u;
  } else {
    float4 u0, u1;
    u0.x = o[0]; u0.y = o[1]; u0.z = o[2]; u0.w = o[3];
    u1.x = o[4]; u1.y = o[5]; u1.z = o[6]; u1.w = o[7];
    float4* o4 = (float4*)((float*)outp + (size_t)row * 512 + c);
    o4[0] = u0; o4[1] = u1;
  }
}

__global__ __launch_bounds__(256) void k_ln_mid(const unsigned short* __restrict__ res,
                                                const unsigned short* __restrict__ add,
                                                const float* __restrict__ w,
                                                const float* __restrict__ bb,
                                                unsigned short* __restrict__ outp) {
  ln_body<0, 4>(res, add, w, bb, outp);
}
__global__ __launch_bounds__(256) void k_ln_out(const unsigned short* __restrict__ res,
                                                const unsigned short* __restrict__ add,
                                                const float* __restrict__ w,
                                                const float* __restrict__ bb,
                                                float* __restrict__ outp) {
  ln_body<1, 4>(res, add, w, bb, outp);
}

extern "C" void kernel_launch(void* const* d_in, const int* in_sizes, int n_in,
                              void* d_out, int out_size, void* d_ws, size_t ws_size,
                              hipStream_t stream) {
  const float* z    = (const float*)d_in[0];
  const float* Wq   = (const float*)d_in[1];
  const float* bq   = (const float*)d_in[2];
  const float* Wk   = (const float*)d_in[3];
  const float* bk   = (const float*)d_in[4];
  const float* Wv   = (const float*)d_in[5];
  const float* bv   = (const float*)d_in[6];
  const float* Wo   = (const float*)d_in[7];
  const float* bo   = (const float*)d_in[8];
  const float* ln1w = (const float*)d_in[9];
  const float* ln1b = (const float*)d_in[10];
  const float* W1   = (const float*)d_in[11];
  const float* b1   = (const float*)d_in[12];
  const float* W2   = (const float*)d_in[13];
  const float* b2   = (const float*)d_in[14];
  const float* ln2w = (const float*)d_in[15];
  const float* ln2b = (const float*)d_in[16];
  float* out = (float*)d_out;

  char* ws = (char*)d_ws;
  size_t off = 0;
  auto alloc = [&](size_t bytes) {
    char* p = ws + off;
    off += (bytes + 255) & ~(size_t)255;
    return p;
  };
  unsigned short* Wsq   = (unsigned short*)alloc((size_t)2048 * 512 * 2);  // WqT|WkT|WvT|WoT
  unsigned short* WTqkv = Wsq;
  unsigned short* WoT   = Wsq + (size_t)1536 * 512;
  unsigned short* W1T   = (unsigned short*)alloc((size_t)2048 * 512 * 2);
  unsigned short* W2T   = (unsigned short*)alloc((size_t)512 * 2048 * 2);
  float*          biasqkv = (float*)alloc(1536 * 4);
  unsigned short* zb    = (unsigned short*)alloc((size_t)8192 * 512 * 2);   // stays live thru ln_mid
  unsigned short* z1b   = (unsigned short*)alloc((size_t)8192 * 512 * 2);
  unsigned short* qkvb  = (unsigned short*)alloc((size_t)8192 * 1536 * 2);
  unsigned short* attnb = (unsigned short*)alloc((size_t)8192 * 512 * 2);
  unsigned short* p1    = (unsigned short*)alloc((size_t)4 * 8192 * 512 * 2);  // 4 split-K planes
  unsigned short* ff    = qkvb;  // reuse qkvb+attnb (contiguous 33.5MB; dead after Wo GEMM)

  // single fused prep dispatch (replaces 5 kernels)
  k_prep<<<7169, 256, 0, stream>>>(z, zb, Wq, Wk, Wv, Wo, Wsq, W1, W1T, W2, W2T,
                                   bq, bk, bv, biasqkv);
  // QKV: [8192,512] @ [512,1536] -> qkvb (bf16), 192 blocks
  k_qkv<<<dim3(6, 32), 512, 0, stream>>>(zb, WTqkv, biasqkv, qkvb, 512, 1536);
  // windowed attention
  k_attn<<<1024, 64, 0, stream>>>(qkvb, attnb);
  // Wo proj: [8192,512] @ [512,512], split-K=4 -> p1[0..3], 256 blocks
  k_wo<<<dim3(2, 32, 4), 512, 0, stream>>>(attnb, WoT, bo, p1, 512, 512);
  // z1b = LN(zb + p1[0..3])  (bf16 residual read: -16.7MB vs f32)
  k_ln_mid<<<2048, 256, 0, stream>>>(zb, p1, ln1w, ln1b, z1b);
  // FFN1: [8192,512] @ [512,2048] + GELU -> ff (bf16), 256 blocks
  k_ffn1<<<dim3(8, 32), 512, 0, stream>>>(z1b, W1T, b1, ff, 512, 2048);
  // FFN2: [8192,2048] @ [2048,512], split-K=4 -> p1[0..3], 256 blocks
  k_ffn2<<<dim3(2, 32, 4), 512, 0, stream>>>(ff, W2T, b2, p1, 2048, 512);
  // out = LN(z1b + p1[0..3])  (f32)
  k_ln_out<<<2048, 256, 0, stream>>>(z1b, p1, ln2w, ln2b, out);
}